// Round 1
// baseline (12227.246 us; speedup 1.0000x reference)
//
#include <hip/hip_runtime.h>
#include <cstdint>

#define B_    64
#define T_    2700
#define HID_  128
#define PRE_  32
#define VMAX_ 256

__device__ __forceinline__ float fast_sigmoid(float x) {
    float t = __builtin_amdgcn_exp2f(-1.4426950408889634f * x);
    return __builtin_amdgcn_rcpf(1.0f + t);
}
__device__ __forceinline__ float fast_tanh(float x) {
    // tanh(x) = 1 - 2/(exp2(2x*log2e)+1); safe at +-inf
    float t = __builtin_amdgcn_exp2f(2.885390081777927f * x);
    return 1.0f - 2.0f * __builtin_amdgcn_rcpf(t + 1.0f);
}
__device__ __forceinline__ void fma4(float4& a, const float4 w, const float4 h) {
    a.x += w.x * h.x; a.y += w.y * h.y; a.z += w.z * h.z; a.w += w.w * h.w;
}

// ---------------------------------------------------------------------------
// Kernel 1: neighborhood assembly + pre = sigmoid(inp @ W_pre.T + b_pre)
// One thread per (b, p, c, i) output element; flat tid == pre output index.
// ---------------------------------------------------------------------------
__global__ __launch_bounds__(256) void k_pre(const float* __restrict__ x,
                                             const float* __restrict__ W_pre,
                                             const float* __restrict__ b_pre,
                                             float* __restrict__ pre_out) {
    int tid  = blockIdx.x * 256 + threadIdx.x;   // < 64*900*3*32
    int i    = tid & 31;
    int rest = tid >> 5;          // (b*900+p)*3 + c
    int c    = rest % 3;
    int r2   = rest / 3;          // b*900 + p
    int p    = r2 % 900;
    int b    = r2 / 900;
    int r    = p / 30;
    int cc   = p - r * 30;
    const float* xb = x + b * 3072 + r * 32 + cc;  // x[b][ch][r][cc] at xb[ch*1024]
    float f0 = xb[0],    f1  = xb[1024], f2  = xb[2048];   // tl
    float f3 = xb[1],    f4  = xb[1025], f5  = xb[2049];   // tc
    float f6 = xb[2],    f7  = xb[1026], f8  = xb[2050];   // tr
    float f9 = xb[32],   f10 = xb[1056], f11 = xb[2080];   // lf
    float ct0 = xb[33],  ct1 = xb[1057];                   // ct[0..1]
    float f12 = (c >= 1) ? ct0 : -1.0f;
    float f13 = (c >= 2) ? ct1 : -1.0f;
    const float* w = W_pre + i * 14;
    float d = b_pre[i];
    d += f0*w[0]  + f1*w[1]  + f2*w[2]  + f3*w[3]  + f4*w[4]  + f5*w[5]  + f6*w[6]
       + f7*w[7]  + f8*w[8]  + f9*w[9]  + f10*w[10] + f11*w[11] + f12*w[12] + f13*w[13];
    pre_out[tid] = fast_sigmoid(d);
}

// ---------------------------------------------------------------------------
// Kernel 2: persistent GRU scan. One block per batch element (64 blocks).
// Thread j owns gate-row j: W_ih[j,:] (8xfloat4) and W_hh[j,:] (32xfloat4) in
// VGPRs; h lives in LDS (broadcast reads). 2 barriers/step. pre rows are
// double-buffered in LDS, prefetched by threads 376..383.
// ---------------------------------------------------------------------------
__global__ __launch_bounds__(384) void k_scan(const float* __restrict__ W_ih,
                                              const float* __restrict__ b_ih,
                                              const float* __restrict__ W_hh,
                                              const float* __restrict__ b_hh,
                                              const float* __restrict__ pre_in,
                                              float* __restrict__ hs) {
    __shared__ __align__(16) float sh_h[HID_];
    __shared__ __align__(16) float sh_g[512];      // [0,256): xg+hg ; [256,384): xn ; [384,512): hn
    __shared__ __align__(16) float sh_pre[2][PRE_];
    const int j = threadIdx.x;
    const int b = blockIdx.x;

    float4 wh[32];
    const float4* whp = (const float4*)(W_hh + (size_t)j * HID_);
#pragma unroll
    for (int k = 0; k < 32; ++k) wh[k] = whp[k];
    float4 wi[8];
    const float4* wip = (const float4*)(W_ih + j * PRE_);
#pragma unroll
    for (int k = 0; k < 8; ++k) wi[k] = wip[k];
    const float bih = b_ih[j];
    const float bhh = b_hh[j];

    const float* preb = pre_in + (size_t)b * T_ * PRE_;
    float* hsb = hs + (size_t)b * T_ * HID_;

    if (j < HID_) sh_h[j] = 0.0f;
    if (j < 8) ((float4*)sh_pre[0])[j] = ((const float4*)preb)[j];
    __syncthreads();

    for (int t = 0; t < T_; ++t) {
        const int par = t & 1;
        // issue prefetch of next pre row early (latency hidden by the dots)
        float4 pf;
        const int jp = j - 376;
        if (jp >= 0) {
            int tn = (t + 1 < T_) ? (t + 1) : t;
            pf = ((const float4*)(preb + (size_t)tn * PRE_))[jp];
        }
        // hg_j = b_hh[j] + W_hh[j,:] . h
        float4 ah0 = {0,0,0,0}, ah1 = {0,0,0,0}, ah2 = {0,0,0,0}, ah3 = {0,0,0,0};
        const float4* h4 = (const float4*)sh_h;
#pragma unroll
        for (int k = 0; k < 32; k += 4) {
            fma4(ah0, wh[k],   h4[k]);
            fma4(ah1, wh[k+1], h4[k+1]);
            fma4(ah2, wh[k+2], h4[k+2]);
            fma4(ah3, wh[k+3], h4[k+3]);
        }
        // xg_j = b_ih[j] + W_ih[j,:] . pre[t]
        float4 ax0 = {0,0,0,0}, ax1 = {0,0,0,0};
        const float4* p4 = (const float4*)sh_pre[par];
#pragma unroll
        for (int k = 0; k < 8; k += 2) {
            fma4(ax0, wi[k],   p4[k]);
            fma4(ax1, wi[k+1], p4[k+1]);
        }
        float hg = bhh + (ah0.x + ah0.y + ah0.z + ah0.w) + (ah1.x + ah1.y + ah1.z + ah1.w)
                       + (ah2.x + ah2.y + ah2.z + ah2.w) + (ah3.x + ah3.y + ah3.z + ah3.w);
        float xg = bih + (ax0.x + ax0.y + ax0.z + ax0.w) + (ax1.x + ax1.y + ax1.z + ax1.w);

        if (jp >= 0) ((float4*)sh_pre[par ^ 1])[jp] = pf;
        if (j < 256) sh_g[j] = xg + hg;
        else { sh_g[j] = xg; sh_g[j + 128] = hg; }
        __syncthreads();

        if (j < HID_) {
            float r = fast_sigmoid(sh_g[j]);
            float z = fast_sigmoid(sh_g[HID_ + j]);
            float n = fast_tanh(sh_g[256 + j] + r * sh_g[384 + j]);
            float hprev = sh_h[j];
            float hnew  = n + z * (hprev - n);   // (1-z)*n + z*hprev
            sh_h[j] = hnew;
            hsb[(size_t)t * HID_ + j] = hnew;
        }
        __syncthreads();
    }
}

// ---------------------------------------------------------------------------
// Kernel 3: out = hs @ W_post.T + b_post, scattered into padded NCHWV layout.
// Grid 64*3*4; block handles (b, ch, 8-row band) = 256 pixel positions.
// Thread v owns W_post[v,:] in VGPRs; h row broadcast via LDS. Border -> 0.
// ---------------------------------------------------------------------------
__global__ __launch_bounds__(256) void k_post(const float* __restrict__ W_post,
                                              const float* __restrict__ b_post,
                                              const float* __restrict__ hs,
                                              float* __restrict__ out) {
    __shared__ __align__(16) float sh_h[HID_];
    const int v     = threadIdx.x;
    const int blk   = blockIdx.x;      // 64*3*4
    const int iband = blk & 3;
    const int rest  = blk >> 2;
    const int ch    = rest % 3;
    const int b     = rest / 3;

    float4 wp[32];
    const float4* wpp = (const float4*)(W_post + (size_t)v * HID_);
#pragma unroll
    for (int k = 0; k < 32; ++k) wp[k] = wpp[k];
    const float bp = b_post[v];

    const float* hsb  = hs + (size_t)b * T_ * HID_;
    float* outb = out + (((size_t)b * 3 + ch) * 1024) * 256;   // [i][j][v]

    for (int pos = 0; pos < 256; ++pos) {
        const int i  = iband * 8 + (pos >> 5);
        const int jc = pos & 31;
        const bool interior = (i >= 1) && (i <= 30) && (jc >= 1) && (jc <= 30);
        if (interior) {
            const int t = ((i - 1) * 30 + (jc - 1)) * 3 + ch;
            if (v < HID_) sh_h[v] = hsb[(size_t)t * HID_ + v];
        }
        __syncthreads();
        float val = 0.0f;
        if (interior) {
            float4 a0 = {0,0,0,0}, a1 = {0,0,0,0}, a2 = {0,0,0,0}, a3 = {0,0,0,0};
            const float4* h4 = (const float4*)sh_h;
#pragma unroll
            for (int k = 0; k < 32; k += 4) {
                fma4(a0, wp[k],   h4[k]);
                fma4(a1, wp[k+1], h4[k+1]);
                fma4(a2, wp[k+2], h4[k+2]);
                fma4(a3, wp[k+3], h4[k+3]);
            }
            val = bp + (a0.x + a0.y + a0.z + a0.w) + (a1.x + a1.y + a1.z + a1.w)
                     + (a2.x + a2.y + a2.z + a2.w) + (a3.x + a3.y + a3.z + a3.w);
        }
        outb[(size_t)(i * 32 + jc) * 256 + v] = val;
        __syncthreads();
    }
}

extern "C" void kernel_launch(void* const* d_in, const int* in_sizes, int n_in,
                              void* d_out, int out_size, void* d_ws, size_t ws_size,
                              hipStream_t stream) {
    const float* x      = (const float*)d_in[0];
    const float* W_pre  = (const float*)d_in[1];
    const float* b_pre  = (const float*)d_in[2];
    const float* W_ih   = (const float*)d_in[3];
    const float* b_ih   = (const float*)d_in[4];
    const float* W_hh   = (const float*)d_in[5];
    const float* b_hh   = (const float*)d_in[6];
    const float* W_post = (const float*)d_in[7];
    const float* b_post = (const float*)d_in[8];
    float* out = (float*)d_out;

    // ws layout: pre (64*2700*32 f32 = 22.1 MB) | hs (64*2700*128 f32 = 88.5 MB)
    float* pre_buf = (float*)d_ws;
    float* hs      = pre_buf + (size_t)B_ * T_ * PRE_;

    k_pre <<<21600, 256, 0, stream>>>(x, W_pre, b_pre, pre_buf);
    k_scan<<<64,    384, 0, stream>>>(W_ih, b_ih, W_hh, b_hh, pre_buf, hs);
    k_post<<<768,   256, 0, stream>>>(W_post, b_post, hs, out);
}

// Round 2
// 3607.420 us; speedup vs baseline: 3.3895x; 3.3895x over previous
//
#include <hip/hip_runtime.h>
#include <cstdint>

#define B_    64
#define T_    2700
#define HID_  128
#define PRE_  32
#define VMAX_ 256

__device__ __forceinline__ float fast_sigmoid(float x) {
    float t = __builtin_amdgcn_exp2f(-1.4426950408889634f * x);
    return __builtin_amdgcn_rcpf(1.0f + t);
}
__device__ __forceinline__ float fast_tanh(float x) {
    float t = __builtin_amdgcn_exp2f(2.885390081777927f * x);
    return 1.0f - 2.0f * __builtin_amdgcn_rcpf(t + 1.0f);
}
__device__ __forceinline__ void fma4(float4& a, const float4 w, const float4 h) {
    a.x += w.x * h.x; a.y += w.y * h.y; a.z += w.z * h.z; a.w += w.w * h.w;
}
__device__ __forceinline__ float hsum4(const float4 a) {
    return (a.x + a.y) + (a.z + a.w);
}

// ---------------------------------------------------------------------------
// Kernel 1: neighborhood assembly + pre = sigmoid(inp @ W_pre.T + b_pre)
// ---------------------------------------------------------------------------
__global__ __launch_bounds__(256) void k_pre(const float* __restrict__ x,
                                             const float* __restrict__ W_pre,
                                             const float* __restrict__ b_pre,
                                             float* __restrict__ pre_out) {
    int tid  = blockIdx.x * 256 + threadIdx.x;   // < 64*900*3*32
    int i    = tid & 31;
    int rest = tid >> 5;          // (b*900+p)*3 + c
    int c    = rest % 3;
    int r2   = rest / 3;          // b*900 + p
    int p    = r2 % 900;
    int b    = r2 / 900;
    int r    = p / 30;
    int cc   = p - r * 30;
    const float* xb = x + b * 3072 + r * 32 + cc;  // x[b][ch][r][cc] at xb[ch*1024]
    float f0 = xb[0],    f1  = xb[1024], f2  = xb[2048];   // tl
    float f3 = xb[1],    f4  = xb[1025], f5  = xb[2049];   // tc
    float f6 = xb[2],    f7  = xb[1026], f8  = xb[2050];   // tr
    float f9 = xb[32],   f10 = xb[1056], f11 = xb[2080];   // lf
    float ct0 = xb[33],  ct1 = xb[1057];                   // ct[0..1]
    float f12 = (c >= 1) ? ct0 : -1.0f;
    float f13 = (c >= 2) ? ct1 : -1.0f;
    const float* w = W_pre + i * 14;
    float d = b_pre[i];
    d += f0*w[0]  + f1*w[1]  + f2*w[2]  + f3*w[3]  + f4*w[4]  + f5*w[5]  + f6*w[6]
       + f7*w[7]  + f8*w[8]  + f9*w[9]  + f10*w[10] + f11*w[11] + f12*w[12] + f13*w[13];
    pre_out[tid] = fast_sigmoid(d);
}

// ---------------------------------------------------------------------------
// Kernel 2: persistent GRU scan. One block (512 thr, 8 waves) per batch.
// Thread (u = tid>>2, q = tid&3) owns K-quarter [32q,32q+32) of the three
// gate rows {u, 128+u, 256+u}: 30 float4 of weights in VGPRs (~190 total,
// no spill at __launch_bounds__(512,2)). Quad butterfly (__shfl_xor 1,2)
// reduces partial dots in-register; h state double-buffered in LDS with
// +4-float pad per quarter (bank-staggered) -> ONE barrier per step.
// ---------------------------------------------------------------------------
__global__ __launch_bounds__(512, 2) void k_scan(const float* __restrict__ W_ih,
                                                 const float* __restrict__ b_ih,
                                                 const float* __restrict__ W_hh,
                                                 const float* __restrict__ b_hh,
                                                 const float* __restrict__ pre_in,
                                                 float* __restrict__ hs) {
    __shared__ __align__(16) float sh_h[2][144];   // 4 quarters of 36 (32+4 pad)
    const int tid = threadIdx.x;
    const int u   = tid >> 2;
    const int q   = tid & 3;
    const int b   = blockIdx.x;

    float4 whr[8], whz[8], whn[8];
    {
        const float4* p0 = (const float4*)(W_hh + (size_t)u * HID_ + q * 32);
        const float4* p1 = (const float4*)(W_hh + (size_t)(HID_ + u) * HID_ + q * 32);
        const float4* p2 = (const float4*)(W_hh + (size_t)(2 * HID_ + u) * HID_ + q * 32);
#pragma unroll
        for (int k = 0; k < 8; ++k) { whr[k] = p0[k]; whz[k] = p1[k]; whn[k] = p2[k]; }
    }
    float4 wir[2], wiz[2], win[2];
    {
        const float4* p0 = (const float4*)(W_ih + u * PRE_ + q * 8);
        const float4* p1 = (const float4*)(W_ih + (HID_ + u) * PRE_ + q * 8);
        const float4* p2 = (const float4*)(W_ih + (2 * HID_ + u) * PRE_ + q * 8);
#pragma unroll
        for (int k = 0; k < 2; ++k) { wir[k] = p0[k]; wiz[k] = p1[k]; win[k] = p2[k]; }
    }
    const float br  = b_ih[u] + b_hh[u];
    const float bz  = b_ih[HID_ + u] + b_hh[HID_ + u];
    const float bxn = b_ih[2 * HID_ + u];
    const float bhn = b_hh[2 * HID_ + u];

    const float* preb = pre_in + (size_t)b * T_ * PRE_ + q * 8;
    float* hsb = hs + (size_t)b * T_ * HID_;

    if (tid < 144) { sh_h[0][tid] = 0.0f; sh_h[1][tid] = 0.0f; }
    float4 p0 = ((const float4*)preb)[0];
    float4 p1 = ((const float4*)preb)[1];
    float hu = 0.0f;
    __syncthreads();

    for (int t = 0; t < T_; ++t) {
        // prefetch next pre row slice into regs (consumed next step)
        const int tn = (t + 1 < T_) ? (t + 1) : t;
        const float4* pnext = (const float4*)(preb + (size_t)tn * PRE_);
        float4 np0 = pnext[0];
        float4 np1 = pnext[1];

        // h-dots over this thread's K-quarter
        const float4* h4 = (const float4*)(&sh_h[t & 1][q * 36]);
        float4 ar = {0,0,0,0}, az = {0,0,0,0}, an = {0,0,0,0};
#pragma unroll
        for (int k = 0; k < 8; ++k) {
            float4 hv = h4[k];
            fma4(ar, whr[k], hv);
            fma4(az, whz[k], hv);
            fma4(an, whn[k], hv);
        }
        // pre-dots
        float4 axr = {0,0,0,0}, axz = {0,0,0,0}, axn = {0,0,0,0};
        fma4(axr, wir[0], p0); fma4(axr, wir[1], p1);
        fma4(axz, wiz[0], p0); fma4(axz, wiz[1], p1);
        fma4(axn, win[0], p0); fma4(axn, win[1], p1);

        float sr  = hsum4(ar) + hsum4(axr);
        float sz  = hsum4(az) + hsum4(axz);
        float sxn = hsum4(axn);
        float shn = hsum4(an);
        // quad butterfly: every lane of the quad ends with the full sum
        sr  += __shfl_xor(sr, 1);  sr  += __shfl_xor(sr, 2);
        sz  += __shfl_xor(sz, 1);  sz  += __shfl_xor(sz, 2);
        sxn += __shfl_xor(sxn, 1); sxn += __shfl_xor(sxn, 2);
        shn += __shfl_xor(shn, 1); shn += __shfl_xor(shn, 2);

        float rg   = fast_sigmoid(sr + br);
        float zg   = fast_sigmoid(sz + bz);
        float ng   = fast_tanh(sxn + bxn + rg * (shn + bhn));
        float hnew = ng + zg * (hu - ng);
        hu = hnew;

        if (q == 0) sh_h[(t + 1) & 1][u + (u >> 5) * 4] = hnew;
        __syncthreads();
        // store AFTER the barrier so the vmcnt drain overlaps the next step
        if (q == 0) hsb[(size_t)t * HID_ + u] = hnew;
        p0 = np0; p1 = np1;
    }
}

// ---------------------------------------------------------------------------
// Kernel 3: out = hs @ W_post.T + b_post into padded NCHWV layout.
// Grid 64*3*32: block = (b, ch, row i). Thread v owns W_post[v,:] in VGPRs;
// h rows double-buffered in LDS (threads 224..255 prefetch), one barrier/col.
// ---------------------------------------------------------------------------
__global__ __launch_bounds__(256, 2) void k_post(const float* __restrict__ W_post,
                                                 const float* __restrict__ b_post,
                                                 const float* __restrict__ hs,
                                                 float* __restrict__ out) {
    __shared__ __align__(16) float sh[2][HID_];
    const int v    = threadIdx.x;
    const int blk  = blockIdx.x;       // 64*3*32
    const int i    = blk % 32;
    const int rest = blk / 32;
    const int ch   = rest % 3;
    const int b    = rest / 3;
    float* outb = out + ((size_t)(b * 3 + ch) * 1024 + i * 32) * VMAX_;

    if (i == 0 || i == 31) {
#pragma unroll
        for (int jc = 0; jc < 32; ++jc) outb[jc * VMAX_ + v] = 0.0f;
        return;
    }

    float4 wp[32];
    const float4* wpp = (const float4*)(W_post + (size_t)v * HID_);
#pragma unroll
    for (int k = 0; k < 32; ++k) wp[k] = wpp[k];
    const float bp = b_post[v];

    const float* hsb = hs + (size_t)b * T_ * HID_;
    const int trow = (i - 1) * 30;     // t = (trow + (jc-1))*3 + ch

    // preload jc=1 into sh[1], write border zeros
    if (v >= 224) {
        ((float4*)sh[1])[v - 224] =
            ((const float4*)(hsb + (size_t)(trow * 3 + ch) * HID_))[v - 224];
    }
    outb[0 * VMAX_ + v]  = 0.0f;
    outb[31 * VMAX_ + v] = 0.0f;
    __syncthreads();

    for (int jc = 1; jc <= 30; ++jc) {
        if (v >= 224 && jc < 30) {
            ((float4*)sh[(jc + 1) & 1])[v - 224] =
                ((const float4*)(hsb + (size_t)((trow + jc) * 3 + ch) * HID_))[v - 224];
        }
        float4 a0 = {0,0,0,0}, a1 = {0,0,0,0}, a2 = {0,0,0,0}, a3 = {0,0,0,0};
        const float4* h4 = (const float4*)sh[jc & 1];
#pragma unroll
        for (int k = 0; k < 32; k += 4) {
            fma4(a0, wp[k],     h4[k]);
            fma4(a1, wp[k + 1], h4[k + 1]);
            fma4(a2, wp[k + 2], h4[k + 2]);
            fma4(a3, wp[k + 3], h4[k + 3]);
        }
        outb[jc * VMAX_ + v] = bp + (hsum4(a0) + hsum4(a1)) + (hsum4(a2) + hsum4(a3));
        __syncthreads();
    }
}

extern "C" void kernel_launch(void* const* d_in, const int* in_sizes, int n_in,
                              void* d_out, int out_size, void* d_ws, size_t ws_size,
                              hipStream_t stream) {
    const float* x      = (const float*)d_in[0];
    const float* W_pre  = (const float*)d_in[1];
    const float* b_pre  = (const float*)d_in[2];
    const float* W_ih   = (const float*)d_in[3];
    const float* b_ih   = (const float*)d_in[4];
    const float* W_hh   = (const float*)d_in[5];
    const float* b_hh   = (const float*)d_in[6];
    const float* W_post = (const float*)d_in[7];
    const float* b_post = (const float*)d_in[8];
    float* out = (float*)d_out;

    // ws layout: pre (64*2700*32 f32 = 22.1 MB) | hs (64*2700*128 f32 = 88.5 MB)
    float* pre_buf = (float*)d_ws;
    float* hs      = pre_buf + (size_t)B_ * T_ * PRE_;

    k_pre <<<21600, 256, 0, stream>>>(x, W_pre, b_pre, pre_buf);
    k_scan<<<B_,    512, 0, stream>>>(W_ih, b_ih, W_hh, b_hh, pre_buf, hs);
    k_post<<<6144,  256, 0, stream>>>(W_post, b_post, hs, out);
}

// Round 3
// 2300.091 us; speedup vs baseline: 5.3160x; 1.5684x over previous
//
#include <hip/hip_runtime.h>
#include <cstdint>

#define B_    64
#define T_    2700
#define HID_  128
#define PRE_  32
#define VMAX_ 256

typedef _Float16 half2_t __attribute__((ext_vector_type(2)));
typedef _Float16 h8_t    __attribute__((ext_vector_type(8)));
union H8 { h8_t v; half2_t p[4]; };

#if __has_builtin(__builtin_amdgcn_fdot2)
__device__ __forceinline__ float FDOT2(half2_t a, half2_t b, float c) {
    return __builtin_amdgcn_fdot2(a, b, c, false);
}
#else
__device__ __forceinline__ float FDOT2(half2_t a, half2_t b, float c) {
    return c + (float)a[0] * (float)b[0] + (float)a[1] * (float)b[1];
}
#endif

__device__ __forceinline__ half2_t mk2(float a, float b) {
    half2_t r; r[0] = (_Float16)a; r[1] = (_Float16)b; return r;
}

template<int CTRL>
__device__ __forceinline__ float dpp_add(float x) {
    int t = __builtin_amdgcn_update_dpp(0, __float_as_int(x), CTRL, 0xF, 0xF, true);
    return x + __int_as_float(t);
}

__device__ __forceinline__ float fast_sigmoid(float x) {
    float t = __builtin_amdgcn_exp2f(-1.4426950408889634f * x);
    return __builtin_amdgcn_rcpf(1.0f + t);
}
__device__ __forceinline__ float fast_tanh(float x) {
    float t = __builtin_amdgcn_exp2f(2.885390081777927f * x);
    return 1.0f - 2.0f * __builtin_amdgcn_rcpf(t + 1.0f);
}
__device__ __forceinline__ void fma4(float4& a, const float4 w, const float4 h) {
    a.x += w.x * h.x; a.y += w.y * h.y; a.z += w.z * h.z; a.w += w.w * h.w;
}
__device__ __forceinline__ float hsum4(const float4 a) {
    return (a.x + a.y) + (a.z + a.w);
}

// ---------------------------------------------------------------------------
// Kernel 1: neighborhood assembly + pre = sigmoid(inp @ W_pre.T + b_pre)
// ---------------------------------------------------------------------------
__global__ __launch_bounds__(256) void k_pre(const float* __restrict__ x,
                                             const float* __restrict__ W_pre,
                                             const float* __restrict__ b_pre,
                                             float* __restrict__ pre_out) {
    int tid  = blockIdx.x * 256 + threadIdx.x;   // < 64*900*3*32
    int i    = tid & 31;
    int rest = tid >> 5;          // (b*900+p)*3 + c
    int c    = rest % 3;
    int r2   = rest / 3;          // b*900 + p
    int p    = r2 % 900;
    int b    = r2 / 900;
    int r    = p / 30;
    int cc   = p - r * 30;
    const float* xb = x + b * 3072 + r * 32 + cc;  // x[b][ch][r][cc] at xb[ch*1024]
    float f0 = xb[0],    f1  = xb[1024], f2  = xb[2048];   // tl
    float f3 = xb[1],    f4  = xb[1025], f5  = xb[2049];   // tc
    float f6 = xb[2],    f7  = xb[1026], f8  = xb[2050];   // tr
    float f9 = xb[32],   f10 = xb[1056], f11 = xb[2080];   // lf
    float ct0 = xb[33],  ct1 = xb[1057];                   // ct[0..1]
    float f12 = (c >= 1) ? ct0 : -1.0f;
    float f13 = (c >= 2) ? ct1 : -1.0f;
    const float* w = W_pre + i * 14;
    float d = b_pre[i];
    d += f0*w[0]  + f1*w[1]  + f2*w[2]  + f3*w[3]  + f4*w[4]  + f5*w[5]  + f6*w[6]
       + f7*w[7]  + f8*w[8]  + f9*w[9]  + f10*w[10] + f11*w[11] + f12*w[12] + f13*w[13];
    pre_out[tid] = fast_sigmoid(d);
}

// ---------------------------------------------------------------------------
// Kernel 2: persistent GRU scan. One block (512 thr) per batch. Thread
// (u=tid>>2, q=tid&3) owns K-quarter [32q,32q+32) of gate rows {u,128+u,
// 256+u} as fp16 pairs (60 weight VGPRs, ~110 total -> NO SPILL). Dots via
// v_dot2_f32_f16 (fp32 accum); quad reduction via DPP quad_perm (pure VALU,
// no ds_bpermute); h state double-buffered fp16 in LDS (reads are 16-way
// broadcast b128s, conflict-free). ONE barrier per step.
// ---------------------------------------------------------------------------
__global__ __launch_bounds__(512, 1) void k_scan(const float* __restrict__ W_ih,
                                                 const float* __restrict__ b_ih,
                                                 const float* __restrict__ W_hh,
                                                 const float* __restrict__ b_hh,
                                                 const float* __restrict__ pre_in,
                                                 float* __restrict__ hs) {
    __shared__ __align__(16) _Float16 sh_h[2][HID_];
    const int tid = threadIdx.x;
    const int u   = tid >> 2;
    const int q   = tid & 3;
    const int b   = blockIdx.x;

    half2_t whr[16], whz[16], whn[16];
    {
        const float4* pr = (const float4*)(W_hh + (size_t)u * HID_ + q * 32);
        const float4* pz = (const float4*)(W_hh + (size_t)(HID_ + u) * HID_ + q * 32);
        const float4* pn = (const float4*)(W_hh + (size_t)(2 * HID_ + u) * HID_ + q * 32);
#pragma unroll
        for (int k = 0; k < 8; ++k) {
            float4 f = pr[k]; whr[2*k] = mk2(f.x, f.y); whr[2*k+1] = mk2(f.z, f.w);
        }
#pragma unroll
        for (int k = 0; k < 8; ++k) {
            float4 f = pz[k]; whz[2*k] = mk2(f.x, f.y); whz[2*k+1] = mk2(f.z, f.w);
        }
#pragma unroll
        for (int k = 0; k < 8; ++k) {
            float4 f = pn[k]; whn[2*k] = mk2(f.x, f.y); whn[2*k+1] = mk2(f.z, f.w);
        }
    }
    half2_t wir[4], wiz[4], win[4];
    {
        const float4* pr = (const float4*)(W_ih + u * PRE_ + q * 8);
        const float4* pz = (const float4*)(W_ih + (HID_ + u) * PRE_ + q * 8);
        const float4* pn = (const float4*)(W_ih + (2 * HID_ + u) * PRE_ + q * 8);
#pragma unroll
        for (int k = 0; k < 2; ++k) {
            float4 f = pr[k]; wir[2*k] = mk2(f.x, f.y); wir[2*k+1] = mk2(f.z, f.w);
            float4 g = pz[k]; wiz[2*k] = mk2(g.x, g.y); wiz[2*k+1] = mk2(g.z, g.w);
            float4 h = pn[k]; win[2*k] = mk2(h.x, h.y); win[2*k+1] = mk2(h.z, h.w);
        }
    }
    const float br  = b_ih[u] + b_hh[u];
    const float bz  = b_ih[HID_ + u] + b_hh[HID_ + u];
    const float bxn = b_ih[2 * HID_ + u];
    const float bhn = b_hh[2 * HID_ + u];

    const float* preb = pre_in + (size_t)b * T_ * PRE_ + q * 8;
    float* hsb = hs + (size_t)b * T_ * HID_;

    if (tid < HID_) { sh_h[0][tid] = (_Float16)0.f; sh_h[1][tid] = (_Float16)0.f; }
    half2_t p[4];
    {
        float4 f0 = ((const float4*)preb)[0];
        float4 f1 = ((const float4*)preb)[1];
        p[0] = mk2(f0.x, f0.y); p[1] = mk2(f0.z, f0.w);
        p[2] = mk2(f1.x, f1.y); p[3] = mk2(f1.z, f1.w);
    }
    float hu = 0.0f;
    __syncthreads();

    for (int t = 0; t < T_; ++t) {
        const int tn = (t + 1 < T_) ? (t + 1) : t;
        const float4* pnx = (const float4*)(preb + (size_t)tn * PRE_);
        float4 nf0 = pnx[0];
        float4 nf1 = pnx[1];

        const h8_t* hblk = (const h8_t*)(&sh_h[t & 1][q * 32]);
        // seed with pre-dots
        float ar0 = FDOT2(wir[0], p[0], 0.f), ar1 = FDOT2(wir[1], p[1], 0.f);
        ar0 = FDOT2(wir[2], p[2], ar0);       ar1 = FDOT2(wir[3], p[3], ar1);
        float az0 = FDOT2(wiz[0], p[0], 0.f), az1 = FDOT2(wiz[1], p[1], 0.f);
        az0 = FDOT2(wiz[2], p[2], az0);       az1 = FDOT2(wiz[3], p[3], az1);
        float axn0 = FDOT2(win[0], p[0], 0.f), axn1 = FDOT2(win[1], p[1], 0.f);
        axn0 = FDOT2(win[2], p[2], axn0);      axn1 = FDOT2(win[3], p[3], axn1);
        float an0 = 0.f, an1 = 0.f;
#pragma unroll
        for (int k = 0; k < 4; ++k) {
            H8 hb; hb.v = hblk[k];
            ar0 = FDOT2(whr[4*k+0], hb.p[0], ar0);
            ar1 = FDOT2(whr[4*k+1], hb.p[1], ar1);
            ar0 = FDOT2(whr[4*k+2], hb.p[2], ar0);
            ar1 = FDOT2(whr[4*k+3], hb.p[3], ar1);
            az0 = FDOT2(whz[4*k+0], hb.p[0], az0);
            az1 = FDOT2(whz[4*k+1], hb.p[1], az1);
            az0 = FDOT2(whz[4*k+2], hb.p[2], az0);
            az1 = FDOT2(whz[4*k+3], hb.p[3], az1);
            an0 = FDOT2(whn[4*k+0], hb.p[0], an0);
            an1 = FDOT2(whn[4*k+1], hb.p[1], an1);
            an0 = FDOT2(whn[4*k+2], hb.p[2], an0);
            an1 = FDOT2(whn[4*k+3], hb.p[3], an1);
        }
        float sr  = ar0 + ar1;
        float sz  = az0 + az1;
        float sxn = axn0 + axn1;
        float shn = an0 + an1;
        sr  = dpp_add<0x4E>(dpp_add<0xB1>(sr));
        sz  = dpp_add<0x4E>(dpp_add<0xB1>(sz));
        sxn = dpp_add<0x4E>(dpp_add<0xB1>(sxn));
        shn = dpp_add<0x4E>(dpp_add<0xB1>(shn));

        float rg   = fast_sigmoid(sr + br);
        float zg   = fast_sigmoid(sz + bz);
        float ng   = fast_tanh(sxn + bxn + rg * (shn + bhn));
        float hnew = ng + zg * (hu - ng);
        hu = hnew;
        if (q == 0) sh_h[(t + 1) & 1][u] = (_Float16)hnew;
        __syncthreads();
        if (q == 0) hsb[(size_t)t * HID_ + u] = hnew;
        p[0] = mk2(nf0.x, nf0.y); p[1] = mk2(nf0.z, nf0.w);
        p[2] = mk2(nf1.x, nf1.y); p[3] = mk2(nf1.z, nf1.w);
    }
}

// ---------------------------------------------------------------------------
// Kernel 3: out = hs @ W_post.T + b_post into padded NCHWV layout.
// Grid 64*3*32: block = (b, ch, row i). 512 threads: 2 threads per output v,
// each owns a 64-float half of W_post[v,:] (64 VGPRs, no spill); DPP xor1
// pair-reduce. h rows double-buffered in LDS.
// ---------------------------------------------------------------------------
__global__ __launch_bounds__(512, 4) void k_post(const float* __restrict__ W_post,
                                                 const float* __restrict__ b_post,
                                                 const float* __restrict__ hs,
                                                 float* __restrict__ out) {
    __shared__ __align__(16) float sh[2][HID_];
    const int tid  = threadIdx.x;
    const int v    = tid >> 1;
    const int hf   = tid & 1;
    const int blk  = blockIdx.x;       // 64*3*32
    const int i    = blk & 31;
    const int rest = blk >> 5;
    const int ch   = rest % 3;
    const int b    = rest / 3;
    float* outb = out + ((size_t)(b * 3 + ch) * 1024 + i * 32) * VMAX_;

    if (i == 0 || i == 31) {
        if (hf == 0) {
#pragma unroll
            for (int jc = 0; jc < 32; ++jc) outb[jc * VMAX_ + v] = 0.0f;
        }
        return;
    }

    float4 wp[16];
    const float4* wpp = (const float4*)(W_post + (size_t)v * HID_ + hf * 64);
#pragma unroll
    for (int k = 0; k < 16; ++k) wp[k] = wpp[k];
    const float bp = b_post[v];

    const float* hsb = hs + (size_t)b * T_ * HID_;
    const int trow = (i - 1) * 30;     // t = (trow + (jc-1))*3 + ch

    if (tid < 32)
        ((float4*)sh[1])[tid] = ((const float4*)(hsb + (size_t)(trow * 3 + ch) * HID_))[tid];
    if (hf == 0) { outb[v] = 0.0f; outb[31 * VMAX_ + v] = 0.0f; }
    __syncthreads();

    for (int jc = 1; jc <= 30; ++jc) {
        if (tid < 32 && jc < 30)
            ((float4*)sh[(jc + 1) & 1])[tid] =
                ((const float4*)(hsb + (size_t)((trow + jc) * 3 + ch) * HID_))[tid];
        const float4* h4 = (const float4*)sh[jc & 1] + hf * 16;
        float4 a0 = {0,0,0,0}, a1 = {0,0,0,0}, a2 = {0,0,0,0}, a3 = {0,0,0,0};
#pragma unroll
        for (int k = 0; k < 16; k += 4) {
            fma4(a0, wp[k],     h4[k]);
            fma4(a1, wp[k + 1], h4[k + 1]);
            fma4(a2, wp[k + 2], h4[k + 2]);
            fma4(a3, wp[k + 3], h4[k + 3]);
        }
        float s = (hsum4(a0) + hsum4(a1)) + (hsum4(a2) + hsum4(a3));
        s = dpp_add<0xB1>(s);
        if (hf == 0) outb[jc * VMAX_ + v] = bp + s;
        __syncthreads();
    }
}

extern "C" void kernel_launch(void* const* d_in, const int* in_sizes, int n_in,
                              void* d_out, int out_size, void* d_ws, size_t ws_size,
                              hipStream_t stream) {
    const float* x      = (const float*)d_in[0];
    const float* W_pre  = (const float*)d_in[1];
    const float* b_pre  = (const float*)d_in[2];
    const float* W_ih   = (const float*)d_in[3];
    const float* b_ih   = (const float*)d_in[4];
    const float* W_hh   = (const float*)d_in[5];
    const float* b_hh   = (const float*)d_in[6];
    const float* W_post = (const float*)d_in[7];
    const float* b_post = (const float*)d_in[8];
    float* out = (float*)d_out;

    // ws layout: pre (64*2700*32 f32 = 22.1 MB) | hs (64*2700*128 f32 = 88.5 MB)
    float* pre_buf = (float*)d_ws;
    float* hs      = pre_buf + (size_t)B_ * T_ * PRE_;

    k_pre <<<21600, 256, 0, stream>>>(x, W_pre, b_pre, pre_buf);
    k_scan<<<B_,    512, 0, stream>>>(W_ih, b_ih, W_hh, b_hh, pre_buf, hs);
    k_post<<<6144,  512, 0, stream>>>(W_post, b_post, hs, out);
}